// Round 1
// baseline (456.277 us; speedup 1.0000x reference)
//
#include <hip/hip_runtime.h>
#include <stdint.h>

typedef float f32x4 __attribute__((ext_vector_type(4)));
typedef float f32x2 __attribute__((ext_vector_type(2)));
typedef short bf16x8 __attribute__((ext_vector_type(8)));

__device__ __forceinline__ uint32_t bf16_rne(float f) {
  uint32_t x = __float_as_uint(f);
  return (x + 0x7FFFu + ((x >> 16) & 1u)) >> 16;
}

__device__ __forceinline__ void load_lds_16B(void* lds_dst, const void* gsrc) {
  __builtin_amdgcn_global_load_lds(
      (const __attribute__((address_space(1))) unsigned int*)gsrc,
      (__attribute__((address_space(3))) unsigned int*)lds_dst, 16, 0, 0);
}

// ---------------- kernel 0: cast x (f32) -> bf16 ----------------
__global__ void cast_x_kernel(const float* __restrict__ x,
                              uint32_t* __restrict__ xb, int n2) {
  int i = blockIdx.x * 256 + threadIdx.x;
  if (i >= n2) return;
  f32x2 v = *(const f32x2*)(x + 2 * i);
  xb[i] = bf16_rne(v[0]) | (bf16_rne(v[1]) << 16);
}

// ---------------- fused per-class GEMM + bias + relu ----------------
// One block: full batch M=256 x N-tile 128 of one class. BK=64, 8 waves.
// A: bf16 [C?][256][K] via global_load_lds (swizzled source).
// B: W f32 [C][K][512] reg-staged -> bf16 -> transposed+swizzled LDS.
template <int K>
__global__ __launch_bounds__(512, 2) void gemm_relu(
    const uint16_t* __restrict__ Abase, long long aClassStride,
    const float* __restrict__ Wbase, const float* __restrict__ biasBase,
    uint16_t* __restrict__ Hout) {
  constexpr int NT = K / 64;
  __shared__ uint8_t smem[2 * 49152 + 512];  // [A 32K | B 16K] x2 + bias

  const int tid = threadIdx.x;
  const int bid = blockIdx.x;
  // XCD-chunk swizzle (2048 % 8 == 0, bijective): class's 4 n-tiles same XCD
  const int logical = ((bid & 7) << 8) | (bid >> 3);
  const int c = logical >> 2;
  const int n0 = (logical & 3) * 128;

  const uint16_t* Ab = Abase + (size_t)c * (size_t)aClassStride;
  const float* Wc = Wbase + (size_t)c * K * 512 + n0;
  const float* bcp = biasBase + (size_t)c * 512 + n0;
  uint16_t* Oc = Hout + (size_t)c * (256 * 512) + n0;

  const int l = tid & 63, w = tid >> 6;
  const int lr = l & 15, lg = l >> 4;
  const int wm = w >> 1, wn = w & 1;  // wave grid 4(M) x 2(N), tile 64x64

  const int aoff_row = (wm * 64 + lr) * 128;
  const int boff_row = 32768 + (wn * 64 + lr) * 128;
  const int kx0 = (lg * 16) ^ ((lr & 7) << 4);  // swizzled k-byte, kk=0

  const int bcg = tid & 31;  // B-stage col group
  const int brp = tid >> 5;  // B-stage row-pair 0..15

  f32x4 acc[4][4];
#pragma unroll
  for (int i = 0; i < 4; i++)
#pragma unroll
    for (int j = 0; j < 4; j++) acc[i][j] = {0.f, 0.f, 0.f, 0.f};

  auto stageA = [&](int ts, int buf) {
    uint8_t* base = smem + buf * 49152;
    const uint16_t* As = Ab + ts * 64;
#pragma unroll
    for (int i = 0; i < 4; i++) {
      int idx = tid + i * 512;          // chunk id 0..2047
      int m = idx >> 3, cc = idx & 7;   // row, 16B-chunk within row
      int ccs = cc ^ (m & 7);           // pre-swizzled source chunk
      load_lds_16B(base + ((w * 64 + i * 512) << 4),
                   As + (size_t)m * K + ccs * 8);
    }
  };
  auto loadB = [&](int ts, f32x4* br) {
    const float* Ws = Wc + (size_t)(ts * 64) * 512;
    br[0] = *(const f32x4*)(Ws + (size_t)(2 * brp) * 512 + 4 * bcg);
    br[1] = *(const f32x4*)(Ws + (size_t)(2 * brp + 1) * 512 + 4 * bcg);
    br[2] = *(const f32x4*)(Ws + (size_t)(2 * brp + 32) * 512 + 4 * bcg);
    br[3] = *(const f32x4*)(Ws + (size_t)(2 * brp + 33) * 512 + 4 * bcg);
  };
  auto writeB = [&](const f32x4* br, int buf) {
    uint8_t* base = smem + buf * 49152 + 32768;
#pragma unroll
    for (int u = 0; u < 2; u++) {
      int rp = brp + u * 16;
#pragma unroll
      for (int j = 0; j < 4; j++) {
        int n = 4 * bcg + j;
        uint32_t p = bf16_rne(br[2 * u][j]) | (bf16_rne(br[2 * u + 1][j]) << 16);
        *(uint32_t*)(base + n * 128 + ((4 * rp) ^ ((n & 7) << 4))) = p;
      }
    }
  };
  auto comp = [&](int buf) {
    const uint8_t* s = smem + buf * 49152;
#pragma unroll
    for (int kk = 0; kk < 2; ++kk) {
      const int kx = kx0 ^ (kk << 6);
      bf16x8 a[4], b[4];
#pragma unroll
      for (int mf = 0; mf < 4; mf++)
        a[mf] = *(const bf16x8*)(s + aoff_row + mf * 2048 + kx);
#pragma unroll
      for (int nf = 0; nf < 4; nf++)
        b[nf] = *(const bf16x8*)(s + boff_row + nf * 2048 + kx);
#pragma unroll
      for (int mf = 0; mf < 4; mf++)
#pragma unroll
        for (int nf = 0; nf < 4; nf++)
          acc[mf][nf] = __builtin_amdgcn_mfma_f32_16x16x32_bf16(
              a[mf], b[nf], acc[mf][nf], 0, 0, 0);
    }
  };

  f32x4 brA[4], brB[4];
  stageA(0, 0);
  loadB(0, brA);
  if (tid < 128) ((float*)(smem + 98304))[tid] = bcp[tid];
  writeB(brA, 0);
  __syncthreads();  // drains A(0) DMA (vmcnt) + write visibility
  stageA(1, 1);
  loadB(1, brB);

#pragma unroll 1
  for (int t = 0; t < NT; t += 2) {
    comp(0);              // tile t, overlaps A(t+1)/B(t+1) in flight
    writeB(brB, 1);       // B(t+1) -> buf1
    __syncthreads();      // drains A(t+1) DMA; buf1 ready
    if (t + 2 < NT) { stageA(t + 2, 0); loadB(t + 2, brA); }
    comp(1);              // tile t+1, overlaps t+2 streaming
    if (t + 2 < NT) {
      writeB(brA, 0);
      __syncthreads();
      if (t + 3 < NT) { stageA(t + 3, 1); loadB(t + 3, brB); }
    }
  }

  // epilogue: bias + relu + bf16 store
  const float* bs = (const float*)(smem + 98304);
#pragma unroll
  for (int mf = 0; mf < 4; mf++) {
#pragma unroll
    for (int nf = 0; nf < 4; nf++) {
      const int col = wn * 64 + nf * 16 + lr;
      const float bv = bs[col];
#pragma unroll
      for (int r = 0; r < 4; r++) {
        const int m = wm * 64 + mf * 16 + lg * 4 + r;
        float v = acc[mf][nf][r] + bv;
        v = fmaxf(v, 0.0f);
        Oc[(size_t)m * 512 + col] = (uint16_t)bf16_rne(v);
      }
    }
  }
}

// ---------------- layer 3: out[b,c,e] = h2[c,b,:].W3[c,:,e] + b3 ----------------
__global__ __launch_bounds__(256) void head_kernel(
    const uint16_t* __restrict__ h2, const float* __restrict__ W3,
    const float* __restrict__ b3, float* __restrict__ out) {
  __shared__ float w3s[1024];
  __shared__ float b3s[2];
  const int c = blockIdx.x, t = threadIdx.x;
#pragma unroll
  for (int i = 0; i < 4; i++) w3s[t + i * 256] = W3[(size_t)c * 1024 + t + i * 256];
  if (t < 2) b3s[t] = b3[c * 2 + t];
  __syncthreads();
  const uint16_t* row = h2 + (size_t)c * 131072 + (size_t)t * 512;
  float a0 = b3s[0], a1 = b3s[1];
  for (int d = 0; d < 512; d += 8) {
    bf16x8 v = *(const bf16x8*)(row + d);
#pragma unroll
    for (int j = 0; j < 8; j++) {
      float f = __uint_as_float(((uint32_t)(uint16_t)v[j]) << 16);
      a0 += f * w3s[(d + j) * 2];
      a1 += f * w3s[(d + j) * 2 + 1];
    }
  }
  size_t o = ((size_t)t * 512 + c) * 2;  // out [B][C][2]
  out[o] = a0;
  out[o + 1] = a1;
}

extern "C" void kernel_launch(void* const* d_in, const int* in_sizes, int n_in,
                              void* d_out, int out_size, void* d_ws,
                              size_t ws_size, hipStream_t stream) {
  const float* x = (const float*)d_in[0];
  const float* W1 = (const float*)d_in[1];
  const float* b1 = (const float*)d_in[2];
  const float* W2 = (const float*)d_in[3];
  const float* b2 = (const float*)d_in[4];
  const float* W3 = (const float*)d_in[5];
  const float* b3 = (const float*)d_in[6];
  float* out = (float*)d_out;

  uint8_t* ws = (uint8_t*)d_ws;
  const size_t xb_off = 0;
  const size_t h1_off = 393216;                 // 256*768*2
  const size_t h2_off = h1_off + 134217728;     // + 512*256*512*2
  const size_t need = h2_off + 134217728;
  if (ws_size < need) return;  // visible failure if workspace too small

  uint32_t* xb = (uint32_t*)(ws + xb_off);
  uint16_t* h1 = (uint16_t*)(ws + h1_off);
  uint16_t* h2 = (uint16_t*)(ws + h2_off);

  cast_x_kernel<<<dim3(384), dim3(256), 0, stream>>>(x, xb, 98304);
  gemm_relu<768><<<dim3(2048), dim3(512), 0, stream>>>(
      (const uint16_t*)xb, 0LL, W1, b1, h1);
  gemm_relu<512><<<dim3(2048), dim3(512), 0, stream>>>(
      h1, 131072LL, W2, b2, h2);
  head_kernel<<<dim3(512), dim3(256), 0, stream>>>(h2, W3, b3, out);
}

// Round 2
// 408.694 us; speedup vs baseline: 1.1164x; 1.1164x over previous
//
#include <hip/hip_runtime.h>
#include <stdint.h>

typedef float f32x4 __attribute__((ext_vector_type(4)));
typedef float f32x2 __attribute__((ext_vector_type(2)));
typedef short bf16x8 __attribute__((ext_vector_type(8)));
typedef uint32_t u32x4 __attribute__((ext_vector_type(4)));

__device__ __forceinline__ uint32_t bf16_rne(float f) {
  uint32_t x = __float_as_uint(f);
  return (x + 0x7FFFu + ((x >> 16) & 1u)) >> 16;
}

__device__ __forceinline__ void load_lds_16B(void* lds_dst, const void* gsrc) {
  __builtin_amdgcn_global_load_lds(
      (const __attribute__((address_space(1))) unsigned int*)gsrc,
      (__attribute__((address_space(3))) unsigned int*)lds_dst, 16, 0, 0);
}

// ---------------- kernel 0: cast x (f32) -> bf16 ----------------
__global__ void cast_x_kernel(const float* __restrict__ x,
                              uint32_t* __restrict__ xb, int n2) {
  int i = blockIdx.x * 256 + threadIdx.x;
  if (i >= n2) return;
  f32x2 v = *(const f32x2*)(x + 2 * i);
  xb[i] = bf16_rne(v[0]) | (bf16_rne(v[1]) << 16);
}

// ---------------- fused per-class GEMM ----------------
// Block: M=256 (full batch) x N=64 of one class, BK=64, 8 waves (8M x 1N),
// per-wave tile 32x64, acc[2][4] = 32 VGPR. LDS 80 KiB -> 2 blocks/CU.
// A: bf16 via global_load_lds (pre-swizzled source chunks).
// B: W f32, lane owns column n=l, wave owns k-octet w -> 8 coalesced dword
//    loads -> pack 8 bf16 -> one swizzled ds_write_b128 (bank-balanced).
// MODE 0: epilogue bias+relu -> bf16 store.  MODE 1: bias+relu -> W3 dot ->
// shfl-reduce -> f32 partials (layer 3 fused, h2 never materialized).
template <int K, int MODE>
__global__ __launch_bounds__(512, 4) void gemm_fused(
    const uint16_t* __restrict__ Abase, long long aClassStride,
    const float* __restrict__ Wbase, const float* __restrict__ biasBase,
    uint16_t* __restrict__ Hout, const float* __restrict__ W3base,
    float* __restrict__ part) {
  constexpr int NT = K / 64;
  __shared__ uint8_t smem[81920];  // 2 x (A 32K + B 8K)

  const int tid = threadIdx.x;
  const int bid = blockIdx.x;
  // bijective XCD swizzle (4096 % 8 == 0): class's 8 n-tiles on one XCD
  const int logical = ((bid & 7) << 9) | (bid >> 3);
  const int c = logical >> 3;
  const int nt = logical & 7;
  const int n0 = nt * 64;

  const uint16_t* Ab = Abase + (size_t)c * (size_t)aClassStride;
  const float* Wc = Wbase + (size_t)c * (K * 512) + n0;

  const int l = tid & 63, w = tid >> 6;
  const int lr = l & 15, lg = l >> 4;

  f32x4 acc[2][4];
#pragma unroll
  for (int i = 0; i < 2; i++)
#pragma unroll
    for (int j = 0; j < 4; j++) acc[i][j] = {0.f, 0.f, 0.f, 0.f};

  auto stageA = [&](int ts, int buf) {
    uint8_t* base = smem + buf * 40960;
    const uint16_t* As = Ab + ts * 64;
#pragma unroll
    for (int i = 0; i < 4; i++) {
      int idx = tid + i * 512;         // chunk id 0..2047
      int m = idx >> 3, cc = idx & 7;  // row, 16B chunk within row
      int ccs = cc ^ (m & 7);          // pre-swizzled source chunk
      load_lds_16B(base + ((w * 64 + i * 512) << 4),
                   As + (size_t)m * K + ccs * 8);
    }
  };
  auto loadB = [&](int ts, float* g) {
    const float* Ws = Wc + (size_t)(ts * 64 + w * 8) * 512 + l;
#pragma unroll
    for (int r = 0; r < 8; r++) g[r] = Ws[(size_t)r * 512];
  };
  auto writeB = [&](const float* g, int buf) {
    u32x4 p;
#pragma unroll
    for (int j = 0; j < 4; j++)
      p[j] = bf16_rne(g[2 * j]) | (bf16_rne(g[2 * j + 1]) << 16);
    *(u32x4*)(smem + buf * 40960 + 32768 + l * 128 + ((w ^ (l & 7)) << 4)) = p;
  };
  auto comp = [&](int buf) {
    const uint8_t* s = smem + buf * 40960;
#pragma unroll
    for (int kk = 0; kk < 2; ++kk) {
      const int kx = ((lg * 16) ^ ((lr & 7) << 4)) ^ (kk << 6);
      bf16x8 a[2], b[4];
#pragma unroll
      for (int mf = 0; mf < 2; mf++)
        a[mf] = *(const bf16x8*)(s + (w * 32 + mf * 16 + lr) * 128 + kx);
#pragma unroll
      for (int nf = 0; nf < 4; nf++)
        b[nf] = *(const bf16x8*)(s + 32768 + (nf * 16 + lr) * 128 + kx);
#pragma unroll
      for (int mf = 0; mf < 2; mf++)
#pragma unroll
        for (int nf = 0; nf < 4; nf++)
          acc[mf][nf] = __builtin_amdgcn_mfma_f32_16x16x32_bf16(
              a[mf], b[nf], acc[mf][nf], 0, 0, 0);
    }
  };

  float g0[8], g1[8];
  stageA(0, 0);
  loadB(0, g0);
  writeB(g0, 0);
  __syncthreads();
  stageA(1, 1);
  loadB(1, g1);

#pragma unroll 1
  for (int t = 0; t < NT; t += 2) {
    comp(0);
    writeB(g1, 1);
    __syncthreads();
    if (t + 2 < NT) { stageA(t + 2, 0); loadB(t + 2, g0); }
    comp(1);
    if (t + 2 < NT) {
      writeB(g0, 0);
      __syncthreads();
      if (t + 3 < NT) { stageA(t + 3, 1); loadB(t + 3, g1); }
    }
  }

  float bv[4];
#pragma unroll
  for (int nf = 0; nf < 4; nf++)
    bv[nf] = biasBase[c * 512 + n0 + nf * 16 + lr];

  if constexpr (MODE == 0) {
    uint16_t* Oc = Hout + (size_t)c * 131072 + n0;
#pragma unroll
    for (int mf = 0; mf < 2; mf++)
#pragma unroll
      for (int nf = 0; nf < 4; nf++)
#pragma unroll
        for (int r = 0; r < 4; r++) {
          int m = w * 32 + mf * 16 + lg * 4 + r;
          float v = fmaxf(acc[mf][nf][r] + bv[nf], 0.f);
          Oc[(size_t)m * 512 + nf * 16 + lr] = (uint16_t)bf16_rne(v);
        }
  } else {
    float w30[4], w31[4];
#pragma unroll
    for (int nf = 0; nf < 4; nf++) {
      f32x2 t = *(const f32x2*)(W3base +
                                ((size_t)c * 512 + n0 + nf * 16 + lr) * 2);
      w30[nf] = t[0];
      w31[nf] = t[1];
    }
#pragma unroll
    for (int mf = 0; mf < 2; mf++)
#pragma unroll
      for (int r = 0; r < 4; r++) {
        float s0 = 0.f, s1 = 0.f;
#pragma unroll
        for (int nf = 0; nf < 4; nf++) {
          float v = fmaxf(acc[mf][nf][r] + bv[nf], 0.f);
          s0 += v * w30[nf];
          s1 += v * w31[nf];
        }
#pragma unroll
        for (int d = 1; d < 16; d <<= 1) {
          s0 += __shfl_xor(s0, d);
          s1 += __shfl_xor(s1, d);
        }
        if (lr == 0) {
          int m = w * 32 + mf * 16 + lg * 4 + r;
          *(f32x2*)(part + (((size_t)c * 256 + m) * 8 + nt) * 2) =
              f32x2{s0, s1};
        }
      }
  }
}

// ---------------- reduce partials -> out [B][C][2] ----------------
__global__ __launch_bounds__(512) void reduce_out(
    const float* __restrict__ part, const float* __restrict__ b3,
    float* __restrict__ out) {
  const int b = blockIdx.x, c = threadIdx.x;
  const f32x4* p = (const f32x4*)(part + ((size_t)c * 256 + b) * 16);
  f32x4 v0 = p[0], v1 = p[1], v2 = p[2], v3 = p[3];
  float s0 = b3[c * 2] + v0[0] + v0[2] + v1[0] + v1[2] + v2[0] + v2[2] +
             v3[0] + v3[2];
  float s1 = b3[c * 2 + 1] + v0[1] + v0[3] + v1[1] + v1[3] + v2[1] + v2[3] +
             v3[1] + v3[3];
  *(f32x2*)(out + ((size_t)b * 512 + c) * 2) = f32x2{s0, s1};
}

extern "C" void kernel_launch(void* const* d_in, const int* in_sizes, int n_in,
                              void* d_out, int out_size, void* d_ws,
                              size_t ws_size, hipStream_t stream) {
  const float* x = (const float*)d_in[0];
  const float* W1 = (const float*)d_in[1];
  const float* b1 = (const float*)d_in[2];
  const float* W2 = (const float*)d_in[3];
  const float* b2 = (const float*)d_in[4];
  const float* W3 = (const float*)d_in[5];
  const float* b3 = (const float*)d_in[6];
  float* out = (float*)d_out;

  uint8_t* ws = (uint8_t*)d_ws;
  const size_t xb_off = 0;
  const size_t h1_off = 393216;              // 256*768*2
  const size_t part_off = h1_off + 134217728;  // + 512*256*512*2
  const size_t need = part_off + 8388608;      // + 512*256*8*2*4
  if (ws_size < need) return;

  uint32_t* xb = (uint32_t*)(ws + xb_off);
  uint16_t* h1 = (uint16_t*)(ws + h1_off);
  float* part = (float*)(ws + part_off);

  cast_x_kernel<<<dim3(384), dim3(256), 0, stream>>>(x, xb, 98304);
  gemm_fused<768, 0><<<dim3(4096), dim3(512), 0, stream>>>(
      (const uint16_t*)xb, 0LL, W1, b1, h1, nullptr, nullptr);
  gemm_fused<512, 1><<<dim3(4096), dim3(512), 0, stream>>>(
      h1, 131072LL, W2, b2, nullptr, W3, part);
  reduce_out<<<dim3(256), dim3(512), 0, stream>>>(part, b3, out);
}